// Round 3
// baseline (2011.603 us; speedup 1.0000x reference)
//
#include <hip/hip_runtime.h>
#include <math.h>

typedef unsigned short u16;
typedef __bf16 v8bf __attribute__((ext_vector_type(8)));
typedef float   v4f  __attribute__((ext_vector_type(4)));

#define T_SEQ 2048
#define HID   5120
#define NH    16
#define DN    128
#define DR    64
#define DV    128
#define QL    1536
#define KVL   512
#define QKV_N (QL + KVL + DR)    // 2112
#define QB_N  (NH * (DN + DR))   // 3072
#define KVB_N (NH * (DN + DV))   // 4096
#define KFULL (KVL + DR)         // 576
#define OD    (NH * DV)          // 2048
#define SCALE_C 0.07216878364870322f       // (DN+DR)^-0.5
#define ROPE_K  0.28782313662425576f       // ln(10000)/32

__device__ __forceinline__ u16 f2b(float f) {
    unsigned int u = __float_as_uint(f);
    return (u16)((u + 0x7fffu + ((u >> 16) & 1u)) >> 16);
}
__device__ __forceinline__ float b2f(u16 b) {
    return __uint_as_float(((unsigned int)b) << 16);
}
__device__ __forceinline__ unsigned int pack2(float a, float b) {
    return (unsigned int)f2b(a) | ((unsigned int)f2b(b) << 16);
}
__device__ __forceinline__ void cstore(float* p, float v) { *p = v; }
__device__ __forceinline__ void cstore(u16* p, float v)   { *p = f2b(v); }

#if __has_builtin(__builtin_amdgcn_global_load_lds)
#define ASYNC_CP16(gp, lp) __builtin_amdgcn_global_load_lds( \
    (__attribute__((address_space(1))) void*)(gp),           \
    (__attribute__((address_space(3))) void*)(lp), 16, 0, 0)
#else
#define ASYNC_CP16(gp, lp) do { *(uint4*)(lp) = *(const uint4*)(gp); } while (0)
#endif

// ---------------------------------------------------------------------------
// f32 -> bf16 elementwise (n4 = count/4)
// ---------------------------------------------------------------------------
__global__ __launch_bounds__(256) void cvt_bf16(
    const float* __restrict__ in, u16* __restrict__ out, int n4)
{
    int i = blockIdx.x * 256 + threadIdx.x;
    if (i < n4) {
        float4 v = ((const float4*)in)[i];
        ushort4 o;
        o.x = f2b(v.x); o.y = f2b(v.y); o.z = f2b(v.z); o.w = f2b(v.w);
        ((ushort4*)out)[i] = o;
    }
}

// ---------------------------------------------------------------------------
// Transpose+convert f32->bf16: out[n][k] (row stride Kd) = in[k][col0+z*zcol+n]
// grid: (Kd/32, Nd/32, Z); 256 threads; 32x32 tiles.
// ---------------------------------------------------------------------------
__global__ __launch_bounds__(256) void transcvt(
    const float* __restrict__ in, u16* __restrict__ out,
    int ldin, int col0, int zcol, long out_z, int Kd)
{
    __shared__ u16 tile[32][33];
    const int bk = blockIdx.x * 32, bn = blockIdx.y * 32, z = blockIdx.z;
    const int r = threadIdx.x >> 3, cg = (threadIdx.x & 7) * 4;
    const float4 v = *(const float4*)(in + (size_t)(bk + r) * ldin + col0 + (size_t)z * zcol + bn + cg);
    tile[r][cg + 0] = f2b(v.x); tile[r][cg + 1] = f2b(v.y);
    tile[r][cg + 2] = f2b(v.z); tile[r][cg + 3] = f2b(v.w);
    __syncthreads();
    ushort4 o;
    o.x = tile[cg + 0][r]; o.y = tile[cg + 1][r];
    o.z = tile[cg + 2][r]; o.w = tile[cg + 3][r];
    *(ushort4*)(out + (size_t)z * out_z + (size_t)(bn + r) * Kd + bk + cg) = o;
}

// ---------------------------------------------------------------------------
// bf16->bf16 transpose: ktT[i][t] = kfull[t][i], i<512. grid (16, 64).
// ---------------------------------------------------------------------------
__global__ __launch_bounds__(256) void transpose_kt(
    const u16* __restrict__ kfull, u16* __restrict__ ktT)
{
    __shared__ u16 tile[32][36];
    const int bi = blockIdx.x * 32, bt = blockIdx.y * 32;
    const int r = threadIdx.x >> 3, cg = (threadIdx.x & 7) * 4;
    ushort4 v = *(const ushort4*)(kfull + (size_t)(bt + r) * KFULL + bi + cg);
    tile[r][cg + 0] = v.x; tile[r][cg + 1] = v.y;
    tile[r][cg + 2] = v.z; tile[r][cg + 3] = v.w;
    __syncthreads();
    ushort4 o;
    o.x = tile[cg + 0][r]; o.y = tile[cg + 1][r];
    o.z = tile[cg + 2][r]; o.w = tile[cg + 3][r];
    *(ushort4*)(ktT + (size_t)(bi + r) * T_SEQ + bt + cg) = o;
}

// ---------------------------------------------------------------------------
// Strided/batched bf16 MFMA GEMM: C = scale * A(bf16, lda) @ Bt(bf16, ldb)^T
// per-z element offsets aoff/boff/coff. 128x128 tile, BK=32, 4 waves.
// M%128==0, K%32==0, Bt rows allocated to 128-multiple; N guarded on store.
// ---------------------------------------------------------------------------
template <typename OT>
__global__ __launch_bounds__(256, 2) void gemm_bt_t(
    const u16* __restrict__ A, long lda, long aoff,
    const u16* __restrict__ Bt, long ldb, long boff,
    OT* __restrict__ C, long ldc, long coff,
    int M, int N, int K, float scale)
{
    __shared__ u16 As[128 * 32], Bs[128 * 32];
    const int z = blockIdx.z;
    A  += (size_t)z * aoff;
    Bt += (size_t)z * boff;
    C  += (size_t)z * coff;
    const int tid = threadIdx.x, lane = tid & 63, wave = tid >> 6;
    const int g = lane >> 4, l15 = lane & 15;
    const int bm = blockIdx.y * 128, bn = blockIdx.x * 128;
    const int wm = (wave & 1) * 64, wn = (wave >> 1) * 64;
    const int srow = tid >> 2, skq = (tid & 3) * 8;
    v4f acc[4][4];
#pragma unroll
    for (int i = 0; i < 4; ++i)
#pragma unroll
        for (int j = 0; j < 4; ++j) acc[i][j] = (v4f){0.f, 0.f, 0.f, 0.f};

    for (int k0 = 0; k0 < K; k0 += 32) {
        ASYNC_CP16(A  + (size_t)(bm + srow) * lda + k0 + skq,      &As[tid * 8]);
        ASYNC_CP16(A  + (size_t)(bm + 64 + srow) * lda + k0 + skq, &As[2048 + tid * 8]);
        ASYNC_CP16(Bt + (size_t)(bn + srow) * ldb + k0 + skq,      &Bs[tid * 8]);
        ASYNC_CP16(Bt + (size_t)(bn + 64 + srow) * ldb + k0 + skq, &Bs[2048 + tid * 8]);
        __syncthreads();
        v8bf af[4], bq[4];
#pragma unroll
        for (int mi = 0; mi < 4; ++mi) af[mi] = *(const v8bf*)&As[(wm + mi * 16 + l15) * 32 + g * 8];
#pragma unroll
        for (int ni = 0; ni < 4; ++ni) bq[ni] = *(const v8bf*)&Bs[(wn + ni * 16 + l15) * 32 + g * 8];
#pragma unroll
        for (int mi = 0; mi < 4; ++mi)
#pragma unroll
            for (int ni = 0; ni < 4; ++ni)
                acc[mi][ni] = __builtin_amdgcn_mfma_f32_16x16x32_bf16(af[mi], bq[ni], acc[mi][ni], 0, 0, 0);
        __syncthreads();
    }
#pragma unroll
    for (int mi = 0; mi < 4; ++mi)
#pragma unroll
        for (int ni = 0; ni < 4; ++ni) {
            const int col = bn + wn + ni * 16 + l15;
            if (col < N) {
#pragma unroll
                for (int r = 0; r < 4; ++r)
                    cstore(&C[(size_t)(bm + wm + mi * 16 + g * 4 + r) * ldc + col],
                           acc[mi][ni][r] * scale);
            }
        }
}

// ---------------------------------------------------------------------------
// Fused rmsnorms + k_pe rope. qkv f32 in; qanorm bf16, kfull bf16 out.
// ---------------------------------------------------------------------------
__global__ __launch_bounds__(256) void norm_rope_kernel(
    const float* __restrict__ qkv, const float* __restrict__ qa_w,
    const float* __restrict__ kva_w, const int* __restrict__ positions,
    u16* __restrict__ qanorm, u16* __restrict__ kfull)
{
    const int t = blockIdx.x, tid = threadIdx.x;
    const float* row = qkv + (size_t)t * QKV_N;
    float sq = 0.f, skv = 0.f;
    for (int i = tid; i < QL; i += 256)  { const float v = row[i];      sq  = fmaf(v, v, sq); }
    for (int i = tid; i < KVL; i += 256) { const float v = row[QL + i]; skv = fmaf(v, v, skv); }
#pragma unroll
    for (int off = 32; off >= 1; off >>= 1) {
        sq  += __shfl_down(sq, off, 64);
        skv += __shfl_down(skv, off, 64);
    }
    __shared__ float red[2][4];
    __shared__ float rs[2];
    const int wv = tid >> 6;
    if ((tid & 63) == 0) { red[0][wv] = sq; red[1][wv] = skv; }
    __syncthreads();
    if (tid == 0) {
        const float a = red[0][0] + red[0][1] + red[0][2] + red[0][3];
        const float b = red[1][0] + red[1][1] + red[1][2] + red[1][3];
        rs[0] = rsqrtf(a / (float)QL + 1e-6f);
        rs[1] = rsqrtf(b / (float)KVL + 1e-6f);
    }
    __syncthreads();
    const float rq = rs[0], rkv = rs[1];
    for (int i = tid; i < QL; i += 256)
        qanorm[(size_t)t * QL + i] = f2b(row[i] * rq * qa_w[i]);
    for (int i = tid; i < KVL; i += 256)
        kfull[(size_t)t * KFULL + i] = f2b(row[QL + i] * rkv * kva_w[i]);
    if (tid < 32) {
        const float pos = (float)positions[t];
        const float inv = __expf(-(float)tid * ROPE_K);
        float s, c;
        __sincosf(pos * inv, &s, &c);
        const float x1 = row[QL + KVL + 2 * tid];
        const float x2 = row[QL + KVL + 2 * tid + 1];
        kfull[(size_t)t * KFULL + KVL + 2 * tid]     = f2b(x1 * c - x2 * s);
        kfull[(size_t)t * KFULL + KVL + 2 * tid + 1] = f2b(x2 * c + x1 * s);
    }
}

// ---------------------------------------------------------------------------
// RoPE on q_pe (bf16 qmat) -> qf[h][t][512:576] bf16, pre-scaled.
// ---------------------------------------------------------------------------
__global__ __launch_bounds__(256) void rope_qpe_kernel(
    const u16* __restrict__ qmat, const int* __restrict__ positions,
    u16* __restrict__ qf)
{
    const int t = blockIdx.x, tid = threadIdx.x;
    const float pos = (float)positions[t];
    for (int p = tid; p < NH * 32; p += 256) {
        const int h = p >> 5, i = p & 31;
        const float inv = __expf(-(float)i * ROPE_K);
        float s, c;
        __sincosf(pos * inv, &s, &c);
        const u16* src = qmat + (size_t)t * QB_N + h * (DN + DR) + DN;
        u16* dst = qf + ((size_t)h * T_SEQ + t) * KFULL + KVL;
        const float x1 = b2f(src[2 * i]), x2 = b2f(src[2 * i + 1]);
        dst[2 * i]     = f2b(SCALE_C * (x1 * c - x2 * s));
        dst[2 * i + 1] = f2b(SCALE_C * (x2 * c + x1 * s));
    }
}

// ---------------------------------------------------------------------------
// Barrier-free MFMA flash attention.
// Block = 32 q-rows x 1 head, 4 waves: wave=(qsub,vh) -> 16 q x 256 v each.
// S operand-swapped (A=K, B=Q-in-regs): softmax state lane-local scalars.
// PV as O^T = V^T * P^T (A=V^T direct from ktT; B=P^T via per-wave LDS tile).
// No __syncthreads in the k-loop; K/V served by L1/L2.
// qf pre-scaled bf16 [NH][T][576]; kfull bf16 [T][576]; ktT bf16 [512][T].
// ---------------------------------------------------------------------------
__global__ __launch_bounds__(256, 2) void attn_v2(
    const u16* __restrict__ qf, const u16* __restrict__ kfull,
    const u16* __restrict__ ktT, u16* __restrict__ o_lat)
{
    __shared__ u16 plds[4 * 16 * 72];   // per-wave P tile [16 q][72-stride]
    const int h = blockIdx.y;
    const int qt0 = (int)(gridDim.x - 1 - blockIdx.x) * 32;   // heavy blocks first
    const int tid = threadIdx.x, lane = tid & 63, wave = tid >> 6;
    const int g = lane >> 4, l15 = lane & 15;
    const int qsub = wave & 1, vh = wave >> 1;
    const int qrow = qt0 + qsub * 16 + l15;
    u16* pl = plds + wave * 16 * 72;

    // Q fragments, register-resident (B-layout: n=l15 -> q row, k=g*8+j)
    v8bf qreg[18];
    const u16* qp = qf + ((size_t)h * T_SEQ + qrow) * KFULL + g * 8;
#pragma unroll
    for (int ch = 0; ch < 18; ++ch) qreg[ch] = *(const v8bf*)(qp + ch * 32);

    v4f acc[16];
#pragma unroll
    for (int vc = 0; vc < 16; ++vc) acc[vc] = (v4f){0.f, 0.f, 0.f, 0.f};
    float m_run = -1e30f, l_run = 0.f;

    const int nk = (qt0 + 32 + 63) / 64;
    const u16* vbase = ktT + (size_t)(vh * 256 + l15) * T_SEQ + g * 8;

    for (int kt = 0; kt < nk; ++kt) {
        const int kt0 = kt * 64;
        // ---- S = K_tile * Q : 4 key-subtiles x 18 k-chunks ----
        v4f sc[4];
#pragma unroll
        for (int s = 0; s < 4; ++s) sc[s] = (v4f){0.f, 0.f, 0.f, 0.f};
#pragma unroll
        for (int s = 0; s < 4; ++s) {
            const u16* kr = kfull + (size_t)(kt0 + s * 16 + l15) * KFULL + g * 8;
#pragma unroll
            for (int ch = 0; ch < 18; ++ch) {
                v8bf kf = *(const v8bf*)(kr + ch * 32);
                sc[s] = __builtin_amdgcn_mfma_f32_16x16x32_bf16(kf, qreg[ch], sc[s], 0, 0, 0);
            }
        }
        // ---- mask + online softmax (lane-local for q=l15) ----
        float p[16];
        float mloc = -1e30f;
#pragma unroll
        for (int s = 0; s < 4; ++s)
#pragma unroll
            for (int r = 0; r < 4; ++r) {
                const int key = kt0 + s * 16 + g * 4 + r;
                const float v = (key <= qrow) ? sc[s][r] : -1e30f;
                p[s * 4 + r] = v;
                mloc = fmaxf(mloc, v);
            }
        mloc = fmaxf(mloc, __shfl_xor(mloc, 16, 64));
        mloc = fmaxf(mloc, __shfl_xor(mloc, 32, 64));
        const float mnew = fmaxf(m_run, mloc);
        const float alpha = __expf(m_run - mnew);
        float rsum = 0.f;
#pragma unroll
        for (int i = 0; i < 16; ++i) { p[i] = __expf(p[i] - mnew); rsum += p[i]; }
        rsum += __shfl_xor(rsum, 16, 64);
        rsum += __shfl_xor(rsum, 32, 64);
        m_run = mnew;
        l_run = l_run * alpha + rsum;
        // ---- write P^T rows to per-wave LDS (no barrier; lgkmcnt only) ----
#pragma unroll
        for (int s = 0; s < 4; ++s) {
            uint2 d;
            d.x = pack2(p[s * 4 + 0], p[s * 4 + 1]);
            d.y = pack2(p[s * 4 + 2], p[s * 4 + 3]);
            *(uint2*)(pl + l15 * 72 + s * 16 + g * 4) = d;
        }
        // ---- rescale O accumulator ----
#pragma unroll
        for (int vc = 0; vc < 16; ++vc) {
            acc[vc][0] *= alpha; acc[vc][1] *= alpha;
            acc[vc][2] *= alpha; acc[vc][3] *= alpha;
        }
        asm volatile("s_waitcnt lgkmcnt(0)" ::: "memory");
        // ---- O^T += V^T P^T ----
        v8bf pf0 = *(const v8bf*)(pl + l15 * 72 + g * 8);
        v8bf pf1 = *(const v8bf*)(pl + l15 * 72 + 32 + g * 8);
        const u16* vb = vbase + kt0;
#pragma unroll
        for (int vc = 0; vc < 16; ++vc) {
            v8bf v0 = *(const v8bf*)(vb + (size_t)vc * 16 * T_SEQ);
            v8bf v1 = *(const v8bf*)(vb + (size_t)vc * 16 * T_SEQ + 32);
            acc[vc] = __builtin_amdgcn_mfma_f32_16x16x32_bf16(v0, pf0, acc[vc], 0, 0, 0);
            acc[vc] = __builtin_amdgcn_mfma_f32_16x16x32_bf16(v1, pf1, acc[vc], 0, 0, 0);
        }
    }
    // ---- normalize + store (acc[vc][r] = O[q=l15][v = vh*256+vc*16+g*4+r]) ----
    const float linv = 1.f / l_run;
    u16* op = o_lat + ((size_t)h * T_SEQ + qrow) * 512 + vh * 256 + g * 4;
#pragma unroll
    for (int vc = 0; vc < 16; ++vc) {
        uint2 d;
        d.x = pack2(acc[vc][0] * linv, acc[vc][1] * linv);
        d.y = pack2(acc[vc][2] * linv, acc[vc][3] * linv);
        *(uint2*)(op + vc * 16) = d;
    }
}

// ---------------------------------------------------------------------------
extern "C" void kernel_launch(void* const* d_in, const int* in_sizes, int n_in,
                              void* d_out, int out_size, void* d_ws, size_t ws_size,
                              hipStream_t stream)
{
    const int*   positions = (const int*)d_in[0];
    const float* hs        = (const float*)d_in[1];
    const float* w_fused   = (const float*)d_in[2];
    const float* w_qb      = (const float*)d_in[3];
    const float* w_kvb     = (const float*)d_in[4];
    const float* w_o       = (const float*)d_in[5];
    const float* qa_w      = (const float*)d_in[6];
    const float* kva_w     = (const float*)d_in[7];
    float* out = (float*)d_out;
    char*  ws  = (char*)d_ws;

    // region plan (bytes), phase-disjoint aliasing:
    // S1 37,748,736: hs_bf (21.0M, dead after qkv GEMM) -> qf
    // S2 33,554,432: wfT(22.28M)+wqbT(9.44M, dead after qmat GEMM) -> o_lat
    // S3 17,301,504: qkv f32 -> o_mid bf16
    // S4 20,971,520: qanorm(6.29M)+qmat(12.58M, dead after rope) -> woT
    // S5 kfull | S6 ktT | S7 wkv_bf | S8 wvcT     total 120,324,096
    char* S1 = ws;
    char* S2 = S1 + 37748736;
    char* S3 = S2 + 33554432;
    char* S4 = S3 + 17301504;
    char* S5 = S4 + 20971520;
    char* S6 = S5 + 2359296;
    char* S7 = S6 + 2097152;
    char* S8 = S7 + 4194304;

    u16*   hs_bf  = (u16*)S1;
    u16*   qf     = (u16*)S1;
    u16*   wfT    = (u16*)S2;                  // 2176 x 5120
    u16*   wqbT   = (u16*)(S2 + 22282240);     // 3072 x 1536
    u16*   o_lat  = (u16*)S2;
    float* qkv    = (float*)S3;
    u16*   o_mid  = (u16*)S3;
    u16*   qanorm = (u16*)S4;
    u16*   qmat   = (u16*)(S4 + 6291456);
    u16*   woT    = (u16*)S4;
    u16*   kfull  = (u16*)S5;
    u16*   ktT    = (u16*)S6;
    u16*   wkv_bf = (u16*)S7;
    u16*   wvcT   = (u16*)S8;

    // 1. conversions
    cvt_bf16<<<(T_SEQ * HID / 4 + 255) / 256, 256, 0, stream>>>(hs, hs_bf, T_SEQ * HID / 4);
    cvt_bf16<<<(KVL * KVB_N / 4 + 255) / 256, 256, 0, stream>>>(w_kvb, wkv_bf, KVL * KVB_N / 4);
    transcvt<<<dim3(HID / 32, QKV_N / 32, 1), 256, 0, stream>>>(w_fused, wfT, QKV_N, 0, 0, 0, HID);
    // 2. qkv = hs @ w_fused (f32 out)
    gemm_bt_t<float><<<dim3(17, 16, 1), 256, 0, stream>>>(
        hs_bf, HID, 0, wfT, HID, 0, qkv, QKV_N, 0, T_SEQ, QKV_N, HID, 1.f);
    // 3. wqbT
    transcvt<<<dim3(QL / 32, QB_N / 32, 1), 256, 0, stream>>>(w_qb, wqbT, QB_N, 0, 0, 0, QL);
    // 4. rmsnorms + k_pe rope
    norm_rope_kernel<<<T_SEQ, 256, 0, stream>>>(qkv, qa_w, kva_w, positions, qanorm, kfull);
    // 5. qmat = qanorm @ w_qb (bf16 out)
    gemm_bt_t<u16><<<dim3(QB_N / 128, 16, 1), 256, 0, stream>>>(
        qanorm, QL, 0, wqbT, QL, 0, qmat, QB_N, 0, T_SEQ, QB_N, QL, 1.f);
    // 6. ktT = kv-latent transposed
    transpose_kt<<<dim3(KVL / 32, T_SEQ / 32), 256, 0, stream>>>(kfull, ktT);
    // 7. absorbed q_nope via batched MFMA (pre-scaled) + q_pe rope
    gemm_bt_t<u16><<<dim3(KVL / 128, 16, NH), 256, 0, stream>>>(
        qmat, QB_N, DN + DR, wkv_bf, KVB_N, DN + DV,
        qf, KFULL, (long)T_SEQ * KFULL, T_SEQ, KVL, DN, SCALE_C);
    rope_qpe_kernel<<<T_SEQ, 256, 0, stream>>>(qmat, positions, qf);
    // 8. wvcT[h][v][l]
    transcvt<<<dim3(KVL / 32, DV / 32, NH), 256, 0, stream>>>(
        w_kvb, wvcT, KVB_N, DN, DN + DV, (long)DV * KVL, KVL);
    // 9. barrier-free MFMA flash attention -> o_lat
    attn_v2<<<dim3(T_SEQ / 32, NH), 256, 0, stream>>>(qf, kfull, ktT, o_lat);
    // 10. o_mid = per-head o_lat @ w_vc (bf16 out)
    gemm_bt_t<u16><<<dim3(1, 16, NH), 256, 0, stream>>>(
        o_lat, 512, (long)T_SEQ * 512, wvcT, 512, (long)DV * 512,
        o_mid, OD, DV, T_SEQ, DV, 512, 1.f);
    // 11. woT + final projection (f32 out)
    transcvt<<<dim3(OD / 32, HID / 32, 1), 256, 0, stream>>>(w_o, woT, HID, 0, 0, 0, OD);
    gemm_bt_t<float><<<dim3(HID / 128, 16, 1), 256, 0, stream>>>(
        o_mid, OD, 0, woT, OD, 0, out, HID, 0, T_SEQ, HID, OD, 1.f);
}